// Round 2
// baseline (327.020 us; speedup 1.0000x reference)
//
#include <hip/hip_runtime.h>
#include <hip/hip_bf16.h>

#define Bc 4
#define Sc 2048
#define Ec 1024
#define Hc 16
#define Dc 64

typedef __bf16 bf16_t;
typedef __bf16 bf16x4 __attribute__((ext_vector_type(4)));
typedef __bf16 bf16x8 __attribute__((ext_vector_type(8)));
typedef float f32x4 __attribute__((ext_vector_type(4)));

extern "C" __device__ float __ocml_native_exp2_f32(float);  // bare v_exp_f32

__device__ __forceinline__ f32x4 mfma16(bf16x8 a, bf16x8 b, f32x4 c) {
    return __builtin_amdgcn_mfma_f32_16x16x32_bf16(a, b, c, 0, 0, 0);
}

// async global->LDS, 16B per lane; LDS dst = wave-uniform base + lane*16
__device__ __forceinline__ void gload16(const bf16_t* g, bf16_t* l) {
    __builtin_amdgcn_global_load_lds(
        (const __attribute__((address_space(1))) unsigned int*)g,
        (__attribute__((address_space(3))) unsigned int*)l, 16, 0, 0);
}

// ---------------------------------------------------------------------------
// f32 -> bf16 elementwise convert (vectorized)
// ---------------------------------------------------------------------------
__global__ __launch_bounds__(256)
void cvt_bf16(const float* __restrict__ in, bf16_t* __restrict__ out, int n4)
{
    int i = blockIdx.x * 256 + threadIdx.x;
    if (i >= n4) return;
    float4 v = ((const float4*)in)[i];
    alignas(8) bf16_t o[4];
    o[0] = (bf16_t)v.x; o[1] = (bf16_t)v.y; o[2] = (bf16_t)v.z; o[3] = (bf16_t)v.w;
    ((uint2*)out)[i] = *(uint2*)o;
}

// ---------------------------------------------------------------------------
// W[K][N] f32 -> Wt[N][K] bf16, 64x64 LDS tiles
// ---------------------------------------------------------------------------
__global__ __launch_bounds__(256)
void transpose_w(const float* __restrict__ W, bf16_t* __restrict__ Wt, int K, int N)
{
    __shared__ float T[64][65];
    const int kt = blockIdx.y, nt = blockIdx.x;
    const int r = threadIdx.x >> 4;          // 0..15
    const int c = (threadIdx.x & 15) * 4;    // 0..60
    #pragma unroll
    for (int p = 0; p < 4; p++) {
        float4 v = *(const float4*)(W + (size_t)(kt*64 + r + p*16)*N + nt*64 + c);
        T[r + p*16][c] = v.x; T[r + p*16][c+1] = v.y;
        T[r + p*16][c+2] = v.z; T[r + p*16][c+3] = v.w;
    }
    __syncthreads();
    #pragma unroll
    for (int p = 0; p < 4; p++) {
        int n = nt*64 + r + p*16;
        alignas(8) bf16_t tmp[4];
        #pragma unroll
        for (int j = 0; j < 4; j++) tmp[j] = (bf16_t)T[c + j][r + p*16];
        *(uint2*)(Wt + (size_t)n*K + kt*64 + c) = *(uint2*)tmp;
    }
}

// ---------------------------------------------------------------------------
// V slice of qkv [token][3E] -> Vt[bh][d][s], natural key order.
// ---------------------------------------------------------------------------
__global__ __launch_bounds__(256)
void transpose_v(const bf16_t* __restrict__ qkv, bf16_t* __restrict__ vt)
{
    __shared__ bf16_t T[64][72];
    const int bh = blockIdx.y, st = blockIdx.x;
    const int b = bh >> 4, h = bh & 15;
    const int sr = threadIdx.x >> 3;         // 0..31
    const int dc = (threadIdx.x & 7) * 8;    // 0..56
    #pragma unroll
    for (int p = 0; p < 2; p++) {
        const bf16_t* src = qkv + (size_t)(b*Sc + st*64 + sr + p*32)*(3*Ec) + 2*Ec + h*Dc + dc;
        *(uint4*)&T[sr + p*32][dc] = *(const uint4*)src;
    }
    __syncthreads();
    const int dr = threadIdx.x >> 3;
    const int sc2 = (threadIdx.x & 7) * 8;
    #pragma unroll
    for (int p = 0; p < 2; p++) {
        alignas(16) bf16_t tmp[8];
        #pragma unroll
        for (int j = 0; j < 8; j++)
            tmp[j] = T[sc2 + j][dr + p*32];
        *(uint4*)(vt + (size_t)bh*Dc*Sc + (size_t)(dr + p*32)*Sc + st*64 + sc2) = *(uint4*)tmp;
    }
}

// ---------------------------------------------------------------------------
// GEMM: C[M,N] = A[M,K]@Bt[N,K]^T + bias. BK=64 as two m97-pattern 32-wide
// sub-buffers, 128x128 tile, global_load_lds 16B staging.
// ---------------------------------------------------------------------------
template<int OUT_IS_F32>
__global__ __launch_bounds__(256)
void gemm_bt(const bf16_t* __restrict__ A, const bf16_t* __restrict__ Bt,
             const float* __restrict__ biasp, void* __restrict__ Cp,
             int M, int N, int K)
{
    __shared__ bf16_t As[2][128*32];
    __shared__ bf16_t Bs[2][128*32];

    const int tid  = threadIdx.x;
    const int wave = tid >> 6;
    const int lane = tid & 63;
    const int quad = lane >> 4;
    const int l16  = lane & 15;
    const int wm   = (wave >> 1) * 64;
    const int wn   = (wave & 1) * 64;
    const int m0   = blockIdx.y * 128;
    const int n0   = blockIdx.x * 128;

    const int srow = wave*32 + (lane >> 2);
    const int scol = (lane & 3) * 8;
    const bf16_t* ap0 = A  + (size_t)(m0 + srow)      * K + scol;
    const bf16_t* ap1 = A  + (size_t)(m0 + srow + 16) * K + scol;
    const bf16_t* bp0 = Bt + (size_t)(n0 + srow)      * K + scol;
    const bf16_t* bp1 = Bt + (size_t)(n0 + srow + 16) * K + scol;
    bf16_t* asl0 = &As[0][(wave*32)      * 32];
    bf16_t* asl1 = &As[0][(wave*32 + 16) * 32];
    bf16_t* bsl0 = &Bs[0][(wave*32)      * 32];
    bf16_t* bsl1 = &Bs[0][(wave*32 + 16) * 32];
    bf16_t* asl2 = &As[1][(wave*32)      * 32];
    bf16_t* asl3 = &As[1][(wave*32 + 16) * 32];
    bf16_t* bsl2 = &Bs[1][(wave*32)      * 32];
    bf16_t* bsl3 = &Bs[1][(wave*32 + 16) * 32];

    f32x4 acc[4][4] = {};

    for (int k0 = 0; k0 < K; k0 += 64) {
        gload16(ap0 + k0,      asl0);
        gload16(ap1 + k0,      asl1);
        gload16(ap0 + k0 + 32, asl2);
        gload16(ap1 + k0 + 32, asl3);
        gload16(bp0 + k0,      bsl0);
        gload16(bp1 + k0,      bsl1);
        gload16(bp0 + k0 + 32, bsl2);
        gload16(bp1 + k0 + 32, bsl3);
        __syncthreads();

        #pragma unroll
        for (int kc = 0; kc < 2; kc++) {
            bf16x8 af[4], bfr[4];
            #pragma unroll
            for (int mi = 0; mi < 4; mi++)
                af[mi] = *(const bf16x8*)&As[kc][(wm + mi*16 + l16)*32 + quad*8];
            #pragma unroll
            for (int ni = 0; ni < 4; ni++)
                bfr[ni] = *(const bf16x8*)&Bs[kc][(wn + ni*16 + l16)*32 + quad*8];
            #pragma unroll
            for (int mi = 0; mi < 4; mi++)
                #pragma unroll
                for (int ni = 0; ni < 4; ni++)
                    acc[mi][ni] = mfma16(af[mi], bfr[ni], acc[mi][ni]);
        }
        __syncthreads();
    }

    float bv[4];
    #pragma unroll
    for (int ni = 0; ni < 4; ni++) bv[ni] = biasp[n0 + wn + ni*16 + l16];

    #pragma unroll
    for (int mi = 0; mi < 4; mi++)
        #pragma unroll
        for (int ni = 0; ni < 4; ni++)
            #pragma unroll
            for (int r = 0; r < 4; r++) {
                int row = m0 + wm + mi*16 + quad*4 + r;
                int col = n0 + wn + ni*16 + l16;
                float v = acc[mi][ni][r] + bv[ni];
                if (OUT_IS_F32) ((float*)Cp)[(size_t)row * N + col] = v;
                else            ((bf16_t*)Cp)[(size_t)row * N + col] = (bf16_t)v;
            }
}

// ---------------------------------------------------------------------------
// Flash attention v9 — attn8 with cross-block overlap.
// R1 counters: dur 75.7us, MfmaUtil 37%, VALUBusy 42%, Occupancy 16.8%,
// HBM 26% — latency/barrier-bound with only 2 blocks/CU (grid 512).
// Fix: q-split 256->128 rows/block (qi 4->2), grid 1024 = 4 blocks/CU,
// __launch_bounds__(256,4); live VGPR drops ~48 (acc/pp/qf halved) so the
// 128-reg cap for 4 waves/SIMD holds. Per-CU MFMA/VALU totals unchanged;
// DS traffic doubles (~30-40% of budget, replacing stall). + T5 setprio
// around MFMA clusters (m191: +4-7% attn).
// ---------------------------------------------------------------------------
__global__ __launch_bounds__(256, 4)
void attn9(const bf16_t* __restrict__ qkv, const bf16_t* __restrict__ vt,
           bf16_t* __restrict__ aout)
{
    __shared__ bf16_t Ks[64][72];      // [key][d]
    __shared__ bf16_t Vs[64][72];      // [d][key]
    __shared__ bf16_t Po[4][16][72];   // per-wave epilogue transpose tile

    const int tid  = threadIdx.x;
    const int wave = tid >> 6;
    const int lane = tid & 63;
    const int quad = lane >> 4;
    const int l16  = lane & 15;
    const int bh   = blockIdx.y;
    const int b    = bh >> 4;
    const int h    = bh & 15;
    const int qt   = blockIdx.x;       // 0..15 (128 q-rows each)
    const float kscale = 0.125f * 1.44269504088896340736f;

    // Q fragments (B-operand: n=q=l16, k=quad*8+j), pre-scaled by kscale
    bf16x8 qf[2][2];
    #pragma unroll
    for (int qi = 0; qi < 2; qi++) {
        const bf16_t* qrow = qkv + (size_t)(b*Sc + qt*128 + wave*32 + qi*16 + l16)*(3*Ec) + h*Dc;
        qf[qi][0] = *(const bf16x8*)(qrow + quad*8);
        qf[qi][1] = *(const bf16x8*)(qrow + 32 + quad*8);
        #pragma unroll
        for (int f = 0; f < 2; f++)
            #pragma unroll
            for (int e = 0; e < 8; e++)
                qf[qi][f][e] = (bf16_t)((float)qf[qi][f][e] * kscale);
    }

    f32x4 acc[4][2] = {};    // O^T accumulator [di][qi]: d=di*16+quad*4+r, q=qi*16+l16
    float lpart[2] = {};     // per-lane partial row sums (this quad's keys)

    const int krw   = tid >> 2;        // 0..63
    const int dbase = (tid & 3) * 16;  // 0/16/32/48

    const bf16_t* kbase = qkv + (size_t)(b*Sc + krw)*(3*Ec) + Ec + h*Dc + dbase;
    const bf16_t* vbase = vt + (size_t)bh*Dc*Sc + (size_t)krw*Sc + dbase;
    const size_t kstep = (size_t)64 * (3*Ec);
    uint4 ku0 = ((const uint4*)kbase)[0];
    uint4 ku1 = ((const uint4*)kbase)[1];
    uint4 vu0 = ((const uint4*)vbase)[0];
    uint4 vu1 = ((const uint4*)vbase)[1];

    for (int kt = 0; kt < Sc/64; kt++) {
        __syncthreads();
        *(uint4*)&Ks[krw][dbase]     = ku0;
        *(uint4*)&Ks[krw][dbase + 8] = ku1;
        *(uint4*)&Vs[krw][dbase]     = vu0;
        *(uint4*)&Vs[krw][dbase + 8] = vu1;
        __syncthreads();

        if (kt < Sc/64 - 1) {
            const bf16_t* kn = kbase + (size_t)(kt+1) * kstep;
            const bf16_t* vn = vbase + (kt+1) * 64;
            ku0 = ((const uint4*)kn)[0];
            ku1 = ((const uint4*)kn)[1];
            vu0 = ((const uint4*)vn)[0];
            vu1 = ((const uint4*)vn)[1];
        }

        // K fragments (A-operand: m=key=l16, k=quad*8+j)
        bf16x8 kf[4][2];
        #pragma unroll
        for (int ki = 0; ki < 4; ki++) {
            kf[ki][0] = *(const bf16x8*)&Ks[ki*16 + l16][quad*8];
            kf[ki][1] = *(const bf16x8*)&Ks[ki*16 + l16][32 + quad*8];
        }

        // S^T = K Q^T ; p = exp2(s) packed bf16, kept in registers
        bf16x4 pp[4][2];   // [ki][qi]: reg r = key ki*16+quad*4+r, col q=l16
        #pragma unroll
        for (int ki = 0; ki < 4; ki++) {
            #pragma unroll
            for (int qi = 0; qi < 2; qi++) {
                __builtin_amdgcn_s_setprio(1);
                f32x4 z = {};
                z = mfma16(kf[ki][0], qf[qi][0], z);
                z = mfma16(kf[ki][1], qf[qi][1], z);
                __builtin_amdgcn_s_setprio(0);
                float p0 = __ocml_native_exp2_f32(z[0]);
                float p1 = __ocml_native_exp2_f32(z[1]);
                float p2 = __ocml_native_exp2_f32(z[2]);
                float p3 = __ocml_native_exp2_f32(z[3]);
                lpart[qi] += (p0 + p1) + (p2 + p3);
                bf16x4 w;
                w[0] = (bf16_t)p0; w[1] = (bf16_t)p1;
                w[2] = (bf16_t)p2; w[3] = (bf16_t)p3;
                pp[ki][qi] = w;
            }
        }

        // O^T += V^T P^T : paired-K packing, keys c*32.. covered per c
        #pragma unroll
        for (int c = 0; c < 2; c++) {
            bf16x8 pcat[2];
            #pragma unroll
            for (int qi = 0; qi < 2; qi++)
                pcat[qi] = __builtin_shufflevector(pp[2*c][qi], pp[2*c+1][qi],
                                                   0,1,2,3,4,5,6,7);
            #pragma unroll
            for (int di = 0; di < 4; di++) {
                bf16x4 v0 = *(const bf16x4*)&Vs[di*16 + l16][c*32 + 4*quad];
                bf16x4 v1 = *(const bf16x4*)&Vs[di*16 + l16][c*32 + 16 + 4*quad];
                bf16x8 vf = __builtin_shufflevector(v0, v1, 0,1,2,3,4,5,6,7);
                __builtin_amdgcn_s_setprio(1);
                #pragma unroll
                for (int qi = 0; qi < 2; qi++)
                    acc[di][qi] = mfma16(vf, pcat[qi], acc[di][qi]);
                __builtin_amdgcn_s_setprio(0);
            }
        }
    }

    // ---- epilogue: reduce l across quads (keys), normalize, transpose via
    // per-wave LDS slice, coalesced stores ----
    float inv[2];
    #pragma unroll
    for (int qi = 0; qi < 2; qi++) {
        float l = lpart[qi];
        l += __shfl_xor(l, 16);
        l += __shfl_xor(l, 32);
        inv[qi] = 1.0f / l;
    }

    const int qrd  = lane >> 2;          // 0..15: token row within qi-slice
    const int dch  = (lane & 3) * 16;    // d chunk for read-back
    #pragma unroll
    for (int qi = 0; qi < 2; qi++) {
        // write O^T slice: Po[q=l16][d=di*16+quad*4 .. +3] (b64, 2-way free)
        #pragma unroll
        for (int di = 0; di < 4; di++) {
            alignas(8) bf16_t w[4];
            #pragma unroll
            for (int r = 0; r < 4; r++)
                w[r] = (bf16_t)(acc[di][qi][r] * inv[qi]);
            *(uint2*)&Po[wave][l16][di*16 + quad*4] = *(uint2*)w;
        }
        asm volatile("s_waitcnt lgkmcnt(0)" ::: "memory");
        // read back token-major, store coalesced (4 lanes = 128B per token)
        uint4 o0 = *(const uint4*)&Po[wave][qrd][dch];
        uint4 o1 = *(const uint4*)&Po[wave][qrd][dch + 8];
        bf16_t* dst = aout + (size_t)(b*Sc + qt*128 + wave*32 + qi*16 + qrd)*Ec + h*Dc + dch;
        ((uint4*)dst)[0] = o0;
        ((uint4*)dst)[1] = o1;
        // WAR safe across qi: DS pipe executes a wave's ops in order
    }
}

extern "C" void kernel_launch(void* const* d_in, const int* in_sizes, int n_in,
                              void* d_out, int out_size, void* d_ws, size_t ws_size,
                              hipStream_t stream) {
    const float* query = (const float*)d_in[0];
    const float* W_qkv = (const float*)d_in[3];
    const float* b_qkv = (const float*)d_in[4];
    const float* W_out = (const float*)d_in[5];
    const float* b_out = (const float*)d_in[6];
    float* out = (float*)d_out;

    const size_t MT = (size_t)Bc * Sc;             // 8192 tokens
    char* ws = (char*)d_ws;
    size_t off = 0;
    bf16_t* qbf    = (bf16_t*)(ws + off); off += MT*Ec*2;            // query bf16 / attn out
    bf16_t* qkv_ws = (bf16_t*)(ws + off); off += MT*3*Ec*2;
    bf16_t* vt_ws  = (bf16_t*)(ws + off); off += MT*Ec*2;
    bf16_t* wqkv_t = (bf16_t*)(ws + off); off += (size_t)3*Ec*Ec*2;
    bf16_t* wout_t = (bf16_t*)(ws + off); off += (size_t)Ec*Ec*2;

    cvt_bf16<<<(MT*Ec/4 + 255)/256, 256, 0, stream>>>(query, qbf, (int)(MT*Ec/4));
    transpose_w<<<dim3(3*Ec/64, Ec/64), 256, 0, stream>>>(W_qkv, wqkv_t, Ec, 3*Ec);
    transpose_w<<<dim3(Ec/64, Ec/64), 256, 0, stream>>>(W_out, wout_t, Ec, Ec);

    gemm_bt<0><<<dim3(3*Ec/128, MT/128), 256, 0, stream>>>(
        qbf, wqkv_t, b_qkv, qkv_ws, (int)MT, 3*Ec, Ec);

    transpose_v<<<dim3(Sc/64, Bc*Hc), 256, 0, stream>>>(qkv_ws, vt_ws);

    attn9<<<dim3(Sc/128, Bc*Hc), 256, 0, stream>>>(qkv_ws, vt_ws, qbf);

    gemm_bt<1><<<dim3(Ec/128, MT/128), 256, 0, stream>>>(
        qbf, wout_t, b_out, out, (int)MT, Ec, Ec);
}

// Round 3
// 318.752 us; speedup vs baseline: 1.0259x; 1.0259x over previous
//
#include <hip/hip_runtime.h>
#include <hip/hip_bf16.h>

#define Bc 4
#define Sc 2048
#define Ec 1024
#define Hc 16
#define Dc 64

typedef __bf16 bf16_t;
typedef __bf16 bf16x4 __attribute__((ext_vector_type(4)));
typedef __bf16 bf16x8 __attribute__((ext_vector_type(8)));
typedef float f32x4 __attribute__((ext_vector_type(4)));

extern "C" __device__ float __ocml_native_exp2_f32(float);  // bare v_exp_f32

__device__ __forceinline__ f32x4 mfma16(bf16x8 a, bf16x8 b, f32x4 c) {
    return __builtin_amdgcn_mfma_f32_16x16x32_bf16(a, b, c, 0, 0, 0);
}

// async global->LDS, 16B per lane; LDS dst = wave-uniform base + lane*16
__device__ __forceinline__ void gload16(const bf16_t* g, bf16_t* l) {
    __builtin_amdgcn_global_load_lds(
        (const __attribute__((address_space(1))) unsigned int*)g,
        (__attribute__((address_space(3))) unsigned int*)l, 16, 0, 0);
}

#define FENCE asm volatile("" ::: "memory")
#define BARRIER do { FENCE; __builtin_amdgcn_s_barrier(); FENCE; } while (0)

// ---------------------------------------------------------------------------
// f32 -> bf16 elementwise convert (vectorized)
// ---------------------------------------------------------------------------
__global__ __launch_bounds__(256)
void cvt_bf16(const float* __restrict__ in, bf16_t* __restrict__ out, int n4)
{
    int i = blockIdx.x * 256 + threadIdx.x;
    if (i >= n4) return;
    float4 v = ((const float4*)in)[i];
    alignas(8) bf16_t o[4];
    o[0] = (bf16_t)v.x; o[1] = (bf16_t)v.y; o[2] = (bf16_t)v.z; o[3] = (bf16_t)v.w;
    ((uint2*)out)[i] = *(uint2*)o;
}

// ---------------------------------------------------------------------------
// W[K][N] f32 -> Wt[N][K] bf16, 64x64 LDS tiles
// ---------------------------------------------------------------------------
__global__ __launch_bounds__(256)
void transpose_w(const float* __restrict__ W, bf16_t* __restrict__ Wt, int K, int N)
{
    __shared__ float T[64][65];
    const int kt = blockIdx.y, nt = blockIdx.x;
    const int r = threadIdx.x >> 4;          // 0..15
    const int c = (threadIdx.x & 15) * 4;    // 0..60
    #pragma unroll
    for (int p = 0; p < 4; p++) {
        float4 v = *(const float4*)(W + (size_t)(kt*64 + r + p*16)*N + nt*64 + c);
        T[r + p*16][c] = v.x; T[r + p*16][c+1] = v.y;
        T[r + p*16][c+2] = v.z; T[r + p*16][c+3] = v.w;
    }
    __syncthreads();
    #pragma unroll
    for (int p = 0; p < 4; p++) {
        int n = nt*64 + r + p*16;
        alignas(8) bf16_t tmp[4];
        #pragma unroll
        for (int j = 0; j < 4; j++) tmp[j] = (bf16_t)T[c + j][r + p*16];
        *(uint2*)(Wt + (size_t)n*K + kt*64 + c) = *(uint2*)tmp;
    }
}

// ---------------------------------------------------------------------------
// V slice of qkv [token][3E] -> Vt[bh][d][s], natural key order.
// ---------------------------------------------------------------------------
__global__ __launch_bounds__(256)
void transpose_v(const bf16_t* __restrict__ qkv, bf16_t* __restrict__ vt)
{
    __shared__ bf16_t T[64][72];
    const int bh = blockIdx.y, st = blockIdx.x;
    const int b = bh >> 4, h = bh & 15;
    const int sr = threadIdx.x >> 3;         // 0..31
    const int dc = (threadIdx.x & 7) * 8;    // 0..56
    #pragma unroll
    for (int p = 0; p < 2; p++) {
        const bf16_t* src = qkv + (size_t)(b*Sc + st*64 + sr + p*32)*(3*Ec) + 2*Ec + h*Dc + dc;
        *(uint4*)&T[sr + p*32][dc] = *(const uint4*)src;
    }
    __syncthreads();
    const int dr = threadIdx.x >> 3;
    const int sc2 = (threadIdx.x & 7) * 8;
    #pragma unroll
    for (int p = 0; p < 2; p++) {
        alignas(16) bf16_t tmp[8];
        #pragma unroll
        for (int j = 0; j < 8; j++)
            tmp[j] = T[sc2 + j][dr + p*32];
        *(uint4*)(vt + (size_t)bh*Dc*Sc + (size_t)(dr + p*32)*Sc + st*64 + sc2) = *(uint4*)tmp;
    }
}

// ---------------------------------------------------------------------------
// gemm256: C[M,N] = A[M,K]@Bt[N,K]^T + bias, bf16 out.
// 8-phase counted-vmcnt schedule (T2+T3+T4+T5 per m201), BM=128 BN=256 BK=64,
// 8 waves (512 thr), LDS 96KB double-buffer, st_16x32 swizzle:
//   pre-swizzled global source -> linear global_load_lds dest -> swizzled
//   ds_read (involution: byte ^= ((byte>>9)&1)<<5, here chunk ^= 2 on row&4).
// Stage spread: p1 B_b(T+1), p3 B_a(T+2), p4 A(T+2); vmcnt(4) once per group.
// Grid 12x64 = 768 blocks = exactly 3 blocks/CU (no quantization tail).
// ---------------------------------------------------------------------------
__global__ __launch_bounds__(512)
void gemm256(const bf16_t* __restrict__ A, const bf16_t* __restrict__ Bt,
             const float* __restrict__ biasp, bf16_t* __restrict__ C,
             int M, int N, int K)
{
    __shared__ bf16_t LA[2][128*64];   // 32 KB
    __shared__ bf16_t LB[2][256*64];   // 64 KB

    const int tid  = threadIdx.x;
    const int wave = tid >> 6;          // 0..7
    const int lane = tid & 63;
    const int quad = lane >> 4;
    const int l16  = lane & 15;
    const int wm   = (wave >> 2) * 64;  // 2 M-waves x 64 rows
    const int wn   = (wave & 3) * 64;   // 4 N-waves x 64 cols
    const int m0   = blockIdx.y * 128;
    const int n0   = blockIdx.x * 256;

    // swizzled ds_read col base: chunk(kk*4+quad) ^ 2 when row&4 (row&4 == l16&4)
    const int qsw   = (quad ^ ((l16 >> 1) & 2)) * 8;          // elems
    // stage source col pre-swizzle: chunk(lane&7) ^ 2 when staged row&4 (== lane&32)
    const int sch   = ((lane & 7) ^ ((lane >> 4) & 2)) * 8;   // elems
    const int srow8 = wave*8 + (lane >> 3);                   // 0..63 within chunk

    const int NT = K >> 6;   // 64-wide K-tiles

    f32x4 acc[4][4] = {};    // [mh*2+mi][nh*2+ni]
    bf16x8 a0[2][2], a1[2][2], b0[2][2], b1[2][2];

    auto stageA = [&](int buf, int kt, int crow) {   // one 64-row chunk, 1 inst
        gload16(A + (size_t)(m0 + crow + srow8)*K + kt*64 + sch,
                &LA[buf][(crow + wave*8)*64]);
    };
    auto stageB = [&](int buf, int kt, int crow) {
        gload16(Bt + (size_t)(n0 + crow + srow8)*K + kt*64 + sch,
                &LB[buf][(crow + wave*8)*64]);
    };

    // ---- prologue: T0 {B_a,B_b,A}, T1 {B_a,A}; last 4 insts may stay in flight
    stageB(0, 0, 0);   stageB(0, 0, 64);
    stageB(0, 0, 128); stageB(0, 0, 192);
    stageA(0, 0, 0);   stageA(0, 0, 64);
    stageB(1, 1, 0);   stageB(1, 1, 64);
    stageA(1, 1, 0);   stageA(1, 1, 64);
    asm volatile("s_waitcnt vmcnt(4)" ::: "memory");
    BARRIER;

    for (int g = 0; g < NT; ++g) {
        const int buf = g & 1;
        // ---------- phase 1: (mh0, nh0); stage B_b(T+1) -> buf^1
        #pragma unroll
        for (int mi = 0; mi < 2; mi++)
            #pragma unroll
            for (int kk = 0; kk < 2; kk++)
                a0[mi][kk] = *(const bf16x8*)&LA[buf][(wm + mi*16 + l16)*64 + kk*32 + qsw];
        #pragma unroll
        for (int ni = 0; ni < 2; ni++)
            #pragma unroll
            for (int kk = 0; kk < 2; kk++)
                b0[ni][kk] = *(const bf16x8*)&LB[buf][(wn + ni*16 + l16)*64 + kk*32 + qsw];
        if (g + 1 < NT) { stageB(buf^1, g+1, 128); stageB(buf^1, g+1, 192); }
        BARRIER;
        asm volatile("s_waitcnt lgkmcnt(0)" ::: "memory");
        __builtin_amdgcn_sched_barrier(0);
        __builtin_amdgcn_s_setprio(1);
        #pragma unroll
        for (int mi = 0; mi < 2; mi++)
            #pragma unroll
            for (int ni = 0; ni < 2; ni++)
                #pragma unroll
                for (int kk = 0; kk < 2; kk++)
                    acc[mi][ni] = mfma16(a0[mi][kk], b0[ni][kk], acc[mi][ni]);
        __builtin_amdgcn_s_setprio(0);
        BARRIER;
        // ---------- phase 2: (mh0, nh1)
        #pragma unroll
        for (int ni = 0; ni < 2; ni++)
            #pragma unroll
            for (int kk = 0; kk < 2; kk++)
                b1[ni][kk] = *(const bf16x8*)&LB[buf][(wn + 32 + ni*16 + l16)*64 + kk*32 + qsw];
        BARRIER;
        asm volatile("s_waitcnt lgkmcnt(0)" ::: "memory");
        __builtin_amdgcn_sched_barrier(0);
        __builtin_amdgcn_s_setprio(1);
        #pragma unroll
        for (int mi = 0; mi < 2; mi++)
            #pragma unroll
            for (int ni = 0; ni < 2; ni++)
                #pragma unroll
                for (int kk = 0; kk < 2; kk++)
                    acc[mi][2+ni] = mfma16(a0[mi][kk], b1[ni][kk], acc[mi][2+ni]);
        __builtin_amdgcn_s_setprio(0);
        BARRIER;
        // ---------- phase 3: (mh1, nh1); stage B_a(T+2) -> buf
        #pragma unroll
        for (int mi = 0; mi < 2; mi++)
            #pragma unroll
            for (int kk = 0; kk < 2; kk++)
                a1[mi][kk] = *(const bf16x8*)&LA[buf][(wm + 32 + mi*16 + l16)*64 + kk*32 + qsw];
        if (g + 2 < NT) { stageB(buf, g+2, 0); stageB(buf, g+2, 64); }
        BARRIER;
        asm volatile("s_waitcnt lgkmcnt(0)" ::: "memory");
        __builtin_amdgcn_sched_barrier(0);
        __builtin_amdgcn_s_setprio(1);
        #pragma unroll
        for (int mi = 0; mi < 2; mi++)
            #pragma unroll
            for (int ni = 0; ni < 2; ni++)
                #pragma unroll
                for (int kk = 0; kk < 2; kk++)
                    acc[2+mi][2+ni] = mfma16(a1[mi][kk], b1[ni][kk], acc[2+mi][2+ni]);
        __builtin_amdgcn_s_setprio(0);
        BARRIER;
        // ---------- phase 4: (mh1, nh0); stage A(T+2) -> buf; counted vmcnt
        if (g + 2 < NT) { stageA(buf, g+2, 0); stageA(buf, g+2, 64); }
        BARRIER;
        __builtin_amdgcn_s_setprio(1);
        #pragma unroll
        for (int mi = 0; mi < 2; mi++)
            #pragma unroll
            for (int ni = 0; ni < 2; ni++)
                #pragma unroll
                for (int kk = 0; kk < 2; kk++)
                    acc[2+mi][ni] = mfma16(a1[mi][kk], b0[ni][kk], acc[2+mi][ni]);
        __builtin_amdgcn_s_setprio(0);
        asm volatile("s_waitcnt vmcnt(4)" ::: "memory");
        BARRIER;
    }

    // ---- epilogue: bias + bf16 store
    float bv[4];
    #pragma unroll
    for (int ni = 0; ni < 4; ni++)
        bv[ni] = biasp[n0 + wn + (ni>>1)*32 + (ni&1)*16 + l16];

    #pragma unroll
    for (int mi = 0; mi < 4; mi++)
        #pragma unroll
        for (int ni = 0; ni < 4; ni++)
            #pragma unroll
            for (int r = 0; r < 4; r++) {
                int row = m0 + wm + (mi>>1)*32 + (mi&1)*16 + quad*4 + r;
                int col = n0 + wn + (ni>>1)*32 + (ni&1)*16 + l16;
                C[(size_t)row * N + col] = (bf16_t)(acc[mi][ni][r] + bv[ni]);
            }
}

// ---------------------------------------------------------------------------
// GEMM (m97-structure, 128x128): kept for the out-projection (N=1024 -> grid
// 8x64 = 512 blocks, 2/CU; the 256-wide tile would leave half the chip idle).
// ---------------------------------------------------------------------------
template<int OUT_IS_F32>
__global__ __launch_bounds__(256)
void gemm_bt(const bf16_t* __restrict__ A, const bf16_t* __restrict__ Bt,
             const float* __restrict__ biasp, void* __restrict__ Cp,
             int M, int N, int K)
{
    __shared__ bf16_t As[2][128*32];
    __shared__ bf16_t Bs[2][128*32];

    const int tid  = threadIdx.x;
    const int wave = tid >> 6;
    const int lane = tid & 63;
    const int quad = lane >> 4;
    const int l16  = lane & 15;
    const int wm   = (wave >> 1) * 64;
    const int wn   = (wave & 1) * 64;
    const int m0   = blockIdx.y * 128;
    const int n0   = blockIdx.x * 128;

    const int srow = wave*32 + (lane >> 2);
    const int scol = (lane & 3) * 8;
    const bf16_t* ap0 = A  + (size_t)(m0 + srow)      * K + scol;
    const bf16_t* ap1 = A  + (size_t)(m0 + srow + 16) * K + scol;
    const bf16_t* bp0 = Bt + (size_t)(n0 + srow)      * K + scol;
    const bf16_t* bp1 = Bt + (size_t)(n0 + srow + 16) * K + scol;
    bf16_t* asl0 = &As[0][(wave*32)      * 32];
    bf16_t* asl1 = &As[0][(wave*32 + 16) * 32];
    bf16_t* bsl0 = &Bs[0][(wave*32)      * 32];
    bf16_t* bsl1 = &Bs[0][(wave*32 + 16) * 32];
    bf16_t* asl2 = &As[1][(wave*32)      * 32];
    bf16_t* asl3 = &As[1][(wave*32 + 16) * 32];
    bf16_t* bsl2 = &Bs[1][(wave*32)      * 32];
    bf16_t* bsl3 = &Bs[1][(wave*32 + 16) * 32];

    f32x4 acc[4][4] = {};

    for (int k0 = 0; k0 < K; k0 += 64) {
        gload16(ap0 + k0,      asl0);
        gload16(ap1 + k0,      asl1);
        gload16(ap0 + k0 + 32, asl2);
        gload16(ap1 + k0 + 32, asl3);
        gload16(bp0 + k0,      bsl0);
        gload16(bp1 + k0,      bsl1);
        gload16(bp0 + k0 + 32, bsl2);
        gload16(bp1 + k0 + 32, bsl3);
        __syncthreads();

        #pragma unroll
        for (int kc = 0; kc < 2; kc++) {
            bf16x8 af[4], bfr[4];
            #pragma unroll
            for (int mi = 0; mi < 4; mi++)
                af[mi] = *(const bf16x8*)&As[kc][(wm + mi*16 + l16)*32 + quad*8];
            #pragma unroll
            for (int ni = 0; ni < 4; ni++)
                bfr[ni] = *(const bf16x8*)&Bs[kc][(wn + ni*16 + l16)*32 + quad*8];
            #pragma unroll
            for (int mi = 0; mi < 4; mi++)
                #pragma unroll
                for (int ni = 0; ni < 4; ni++)
                    acc[mi][ni] = mfma16(af[mi], bfr[ni], acc[mi][ni]);
        }
        __syncthreads();
    }

    float bv[4];
    #pragma unroll
    for (int ni = 0; ni < 4; ni++) bv[ni] = biasp[n0 + wn + ni*16 + l16];

    #pragma unroll
    for (int mi = 0; mi < 4; mi++)
        #pragma unroll
        for (int ni = 0; ni < 4; ni++)
            #pragma unroll
            for (int r = 0; r < 4; r++) {
                int row = m0 + wm + mi*16 + quad*4 + r;
                int col = n0 + wn + ni*16 + l16;
                float v = acc[mi][ni][r] + bv[ni];
                if (OUT_IS_F32) ((float*)Cp)[(size_t)row * N + col] = v;
                else            ((bf16_t*)Cp)[(size_t)row * N + col] = (bf16_t)v;
            }
}

// ---------------------------------------------------------------------------
// Flash attention v8 (reverted from v9: the (256,4) q-split capped VGPR at 64
// -> inner-loop scratch spills, 75.7 -> 98.7us. 128 VGPR / 2 blocks/CU is the
// sweet spot for this structure.)
// S^T = K Q^T; p = exp2(s) packed bf16 in-register; O^T = V^T P^T via
// paired-K packing; epilogue through per-wave LDS tile -> coalesced stores.
// ---------------------------------------------------------------------------
__global__ __launch_bounds__(256, 2)
void attn8(const bf16_t* __restrict__ qkv, const bf16_t* __restrict__ vt,
           bf16_t* __restrict__ aout)
{
    __shared__ bf16_t Ks[64][72];      // [key][d]
    __shared__ bf16_t Vs[64][72];      // [d][key]
    __shared__ bf16_t Po[4][16][72];   // per-wave epilogue transpose tile

    const int tid  = threadIdx.x;
    const int wave = tid >> 6;
    const int lane = tid & 63;
    const int quad = lane >> 4;
    const int l16  = lane & 15;
    const int bh   = blockIdx.y;
    const int b    = bh >> 4;
    const int h    = bh & 15;
    const int qt   = blockIdx.x;       // 0..7 (256 q-rows each)
    const float kscale = 0.125f * 1.44269504088896340736f;

    // Q fragments (B-operand: n=q=l16, k=quad*8+j), pre-scaled by kscale
    bf16x8 qf[4][2];
    #pragma unroll
    for (int qi = 0; qi < 4; qi++) {
        const bf16_t* qrow = qkv + (size_t)(b*Sc + qt*256 + wave*64 + qi*16 + l16)*(3*Ec) + h*Dc;
        qf[qi][0] = *(const bf16x8*)(qrow + quad*8);
        qf[qi][1] = *(const bf16x8*)(qrow + 32 + quad*8);
        #pragma unroll
        for (int f = 0; f < 2; f++)
            #pragma unroll
            for (int e = 0; e < 8; e++)
                qf[qi][f][e] = (bf16_t)((float)qf[qi][f][e] * kscale);
    }

    f32x4 acc[4][4] = {};    // O^T accumulator [di][qi]: d=di*16+quad*4+r, q=qi*16+l16
    float lpart[4] = {};     // per-lane partial row sums (this quad's keys)

    const int krw   = tid >> 2;        // 0..63
    const int dbase = (tid & 3) * 16;  // 0/16/32/48

    const bf16_t* kbase = qkv + (size_t)(b*Sc + krw)*(3*Ec) + Ec + h*Dc + dbase;
    const bf16_t* vbase = vt + (size_t)bh*Dc*Sc + (size_t)krw*Sc + dbase;
    const size_t kstep = (size_t)64 * (3*Ec);
    uint4 ku0 = ((const uint4*)kbase)[0];
    uint4 ku1 = ((const uint4*)kbase)[1];
    uint4 vu0 = ((const uint4*)vbase)[0];
    uint4 vu1 = ((const uint4*)vbase)[1];

    for (int kt = 0; kt < Sc/64; kt++) {
        __syncthreads();
        *(uint4*)&Ks[krw][dbase]     = ku0;
        *(uint4*)&Ks[krw][dbase + 8] = ku1;
        *(uint4*)&Vs[krw][dbase]     = vu0;
        *(uint4*)&Vs[krw][dbase + 8] = vu1;
        __syncthreads();

        if (kt < Sc/64 - 1) {
            const bf16_t* kn = kbase + (size_t)(kt+1) * kstep;
            const bf16_t* vn = vbase + (kt+1) * 64;
            ku0 = ((const uint4*)kn)[0];
            ku1 = ((const uint4*)kn)[1];
            vu0 = ((const uint4*)vn)[0];
            vu1 = ((const uint4*)vn)[1];
        }

        // K fragments (A-operand: m=key=l16, k=quad*8+j)
        bf16x8 kf[4][2];
        #pragma unroll
        for (int ki = 0; ki < 4; ki++) {
            kf[ki][0] = *(const bf16x8*)&Ks[ki*16 + l16][quad*8];
            kf[ki][1] = *(const bf16x8*)&Ks[ki*16 + l16][32 + quad*8];
        }

        // S^T = K Q^T ; p = exp2(s) packed bf16, kept in registers
        bf16x4 pp[4][4];   // [ki][qi]: reg r = key ki*16+quad*4+r, col q=l16
        #pragma unroll
        for (int ki = 0; ki < 4; ki++) {
            #pragma unroll
            for (int qi = 0; qi < 4; qi++) {
                f32x4 z = {};
                z = mfma16(kf[ki][0], qf[qi][0], z);
                z = mfma16(kf[ki][1], qf[qi][1], z);
                float p0 = __ocml_native_exp2_f32(z[0]);
                float p1 = __ocml_native_exp2_f32(z[1]);
                float p2 = __ocml_native_exp2_f32(z[2]);
                float p3 = __ocml_native_exp2_f32(z[3]);
                lpart[qi] += (p0 + p1) + (p2 + p3);
                bf16x4 w;
                w[0] = (bf16_t)p0; w[1] = (bf16_t)p1;
                w[2] = (bf16_t)p2; w[3] = (bf16_t)p3;
                pp[ki][qi] = w;
            }
        }

        // O^T += V^T P^T : paired-K packing, keys c*32.. covered per c
        #pragma unroll
        for (int c = 0; c < 2; c++) {
            bf16x8 pcat[4];
            #pragma unroll
            for (int qi = 0; qi < 4; qi++)
                pcat[qi] = __builtin_shufflevector(pp[2*c][qi], pp[2*c+1][qi],
                                                   0,1,2,3,4,5,6,7);
            #pragma unroll
            for (int di = 0; di < 4; di++) {
                bf16x4 v0 = *(const bf16x4*)&Vs[di*16 + l16][c*32 + 4*quad];
                bf16x4 v1 = *(const bf16x4*)&Vs[di*16 + l16][c*32 + 16 + 4*quad];
                bf16x8 vf = __builtin_shufflevector(v0, v1, 0,1,2,3,4,5,6,7);
                #pragma unroll
                for (int qi = 0; qi < 4; qi++)
                    acc[di][qi] = mfma16(vf, pcat[qi], acc[di][qi]);
            }
        }
    }

    // ---- epilogue: reduce l across quads (keys), normalize, transpose via
    // per-wave LDS slice, coalesced stores ----
    float inv[4];
    #pragma unroll
    for (int qi = 0; qi < 4; qi++) {
        float l = lpart[qi];
        l += __shfl_xor(l, 16);
        l += __shfl_xor(l, 32);
        inv[qi] = 1.0f / l;
    }

    const int qrd  = lane >> 2;          // 0..15: token row within qi-slice
    const int dch  = (lane & 3) * 16;    // d chunk for read-back
    #pragma unroll
    for (int qi = 0; qi < 4; qi++) {
        // write O^T slice: Po[q=l16][d=di*16+quad*4 .. +3] (b64, 2-way free)
        #pragma unroll
        for (int di = 0; di < 4; di++) {
            alignas(8) bf16_t w[4];
            #pragma unroll
            for (int r = 0; r < 4; r++)
                w[r] = (bf16_t)(acc[di][qi][r] * inv[qi]);
            *(uint2*)&Po[wave][l16][di*16 + quad*4] = *(uint2*)w;
        }
        asm volatile("s_waitcnt lgkmcnt(0)" ::: "memory");
        // read back token-major, store coalesced (4 lanes = 128B per token)
        uint4 o0 = *(const uint4*)&Po[wave][qrd][dch];
        uint4 o1 = *(const uint4*)&Po[wave][qrd][dch + 8];
        bf16_t* dst = aout + (size_t)(b*Sc + qt*256 + wave*64 + qi*16 + qrd)*Ec + h*Dc + dch;
        ((uint4*)dst)[0] = o0;
        ((uint4*)dst)[1] = o1;
        // WAR safe across qi: DS pipe executes a wave's ops in order
    }
}

extern "C" void kernel_launch(void* const* d_in, const int* in_sizes, int n_in,
                              void* d_out, int out_size, void* d_ws, size_t ws_size,
                              hipStream_t stream) {
    const float* query = (const float*)d_in[0];
    const float* W_qkv = (const float*)d_in[3];
    const float* b_qkv = (const float*)d_in[4];
    const float* W_out = (const float*)d_in[5];
    const float* b_out = (const float*)d_in[6];
    float* out = (float*)d_out;

    const size_t MT = (size_t)Bc * Sc;             // 8192 tokens
    char* ws = (char*)d_ws;
    size_t off = 0;
    bf16_t* qbf    = (bf16_t*)(ws + off); off += MT*Ec*2;            // query bf16 / attn out
    bf16_t* qkv_ws = (bf16_t*)(ws + off); off += MT*3*Ec*2;
    bf16_t* vt_ws  = (bf16_t*)(ws + off); off += MT*Ec*2;
    bf16_t* wqkv_t = (bf16_t*)(ws + off); off += (size_t)3*Ec*Ec*2;
    bf16_t* wout_t = (bf16_t*)(ws + off); off += (size_t)Ec*Ec*2;

    cvt_bf16<<<(MT*Ec/4 + 255)/256, 256, 0, stream>>>(query, qbf, (int)(MT*Ec/4));
    transpose_w<<<dim3(3*Ec/64, Ec/64), 256, 0, stream>>>(W_qkv, wqkv_t, Ec, 3*Ec);
    transpose_w<<<dim3(Ec/64, Ec/64), 256, 0, stream>>>(W_out, wout_t, Ec, Ec);

    gemm256<<<dim3(3*Ec/256, MT/128), 512, 0, stream>>>(
        qbf, wqkv_t, b_qkv, qkv_ws, (int)MT, 3*Ec, Ec);

    transpose_v<<<dim3(Sc/64, Bc*Hc), 256, 0, stream>>>(qkv_ws, vt_ws);

    attn8<<<dim3(Sc/256, Bc*Hc), 256, 0, stream>>>(qkv_ws, vt_ws, qbf);

    gemm_bt<1><<<dim3(Ec/128, MT/128), 256, 0, stream>>>(
        qbf, wout_t, b_out, out, (int)MT, Ec, Ec);
}

// Round 5
// 301.974 us; speedup vs baseline: 1.0829x; 1.0556x over previous
//
#include <hip/hip_runtime.h>
#include <hip/hip_bf16.h>

#define Bc 4
#define Sc 2048
#define Ec 1024
#define Hc 16
#define Dc 64

typedef __bf16 bf16_t;
typedef __bf16 bf16x4 __attribute__((ext_vector_type(4)));
typedef __bf16 bf16x8 __attribute__((ext_vector_type(8)));
typedef float f32x4 __attribute__((ext_vector_type(4)));

extern "C" __device__ float __ocml_native_exp2_f32(float);  // bare v_exp_f32

__device__ __forceinline__ f32x4 mfma16(bf16x8 a, bf16x8 b, f32x4 c) {
    return __builtin_amdgcn_mfma_f32_16x16x32_bf16(a, b, c, 0, 0, 0);
}

// async global->LDS, 16B per lane; LDS dst = wave-uniform base + lane*16
__device__ __forceinline__ void gload16(const bf16_t* g, bf16_t* l) {
    __builtin_amdgcn_global_load_lds(
        (const __attribute__((address_space(1))) unsigned int*)g,
        (__attribute__((address_space(3))) unsigned int*)l, 16, 0, 0);
}

#define FENCE asm volatile("" ::: "memory")
#define BARRIER do { FENCE; __builtin_amdgcn_s_barrier(); FENCE; } while (0)

// ---------------------------------------------------------------------------
// f32 -> bf16 elementwise convert (vectorized)
// ---------------------------------------------------------------------------
__global__ __launch_bounds__(256)
void cvt_bf16(const float* __restrict__ in, bf16_t* __restrict__ out, int n4)
{
    int i = blockIdx.x * 256 + threadIdx.x;
    if (i >= n4) return;
    float4 v = ((const float4*)in)[i];
    alignas(8) bf16_t o[4];
    o[0] = (bf16_t)v.x; o[1] = (bf16_t)v.y; o[2] = (bf16_t)v.z; o[3] = (bf16_t)v.w;
    ((uint2*)out)[i] = *(uint2*)o;
}

// ---------------------------------------------------------------------------
// W[K][N] f32 -> Wt[N][K] bf16, 64x64 LDS tiles
// ---------------------------------------------------------------------------
__global__ __launch_bounds__(256)
void transpose_w(const float* __restrict__ W, bf16_t* __restrict__ Wt, int K, int N)
{
    __shared__ float T[64][65];
    const int kt = blockIdx.y, nt = blockIdx.x;
    const int r = threadIdx.x >> 4;          // 0..15
    const int c = (threadIdx.x & 15) * 4;    // 0..60
    #pragma unroll
    for (int p = 0; p < 4; p++) {
        float4 v = *(const float4*)(W + (size_t)(kt*64 + r + p*16)*N + nt*64 + c);
        T[r + p*16][c] = v.x; T[r + p*16][c+1] = v.y;
        T[r + p*16][c+2] = v.z; T[r + p*16][c+3] = v.w;
    }
    __syncthreads();
    #pragma unroll
    for (int p = 0; p < 4; p++) {
        int n = nt*64 + r + p*16;
        alignas(8) bf16_t tmp[4];
        #pragma unroll
        for (int j = 0; j < 4; j++) tmp[j] = (bf16_t)T[c + j][r + p*16];
        *(uint2*)(Wt + (size_t)n*K + kt*64 + c) = *(uint2*)tmp;
    }
}

// ---------------------------------------------------------------------------
// V slice of qkv [token][3E] -> Vt[bh][d][s], natural key order.
// ---------------------------------------------------------------------------
__global__ __launch_bounds__(256)
void transpose_v(const bf16_t* __restrict__ qkv, bf16_t* __restrict__ vt)
{
    __shared__ bf16_t T[64][72];
    const int bh = blockIdx.y, st = blockIdx.x;
    const int b = bh >> 4, h = bh & 15;
    const int sr = threadIdx.x >> 3;         // 0..31
    const int dc = (threadIdx.x & 7) * 8;    // 0..56
    #pragma unroll
    for (int p = 0; p < 2; p++) {
        const bf16_t* src = qkv + (size_t)(b*Sc + st*64 + sr + p*32)*(3*Ec) + 2*Ec + h*Dc + dc;
        *(uint4*)&T[sr + p*32][dc] = *(const uint4*)src;
    }
    __syncthreads();
    const int dr = threadIdx.x >> 3;
    const int sc2 = (threadIdx.x & 7) * 8;
    #pragma unroll
    for (int p = 0; p < 2; p++) {
        alignas(16) bf16_t tmp[8];
        #pragma unroll
        for (int j = 0; j < 8; j++)
            tmp[j] = T[sc2 + j][dr + p*32];
        *(uint4*)(vt + (size_t)bh*Dc*Sc + (size_t)(dr + p*32)*Sc + st*64 + sc2) = *(uint4*)tmp;
    }
}

// ---------------------------------------------------------------------------
// gemm3b: C[M,N] = A[M,K]@Bt[N,K]^T + bias.
// Triple-buffered counted-vmcnt schedule (R3 post-mortem redesign):
//   BM=128 BN=256 BK=64, 8 waves (512 thr), per-wave 64x64 out (32 MFMA/phase,
//   4x A-reuse + 4x B-reuse -> LDS:MFMA cyc ~1.65).
//   LDS 3 x (A 16KB + B 32KB) = 144KB; phase t: read buf t%3, stage tile t+2
//   into buf (t+2)%3 (idle since phase t-1, barrier-separated -> WAR safe).
//   vmcnt(6) per phase keeps exactly one 6-inst stage batch in flight (2-phase
//   landing slack, never drains to 0 mid-loop). Chunk-XOR swizzle
//   (chunk ^= (row>>1)&7, pre-swizzled global source) -> ~2-way LDS banks.
//   Grid: QKV 12x64=768 = 3 exact rounds/CU; out-proj 4x64=256 = 1 round.
// ---------------------------------------------------------------------------
template<int OUT_IS_F32>
__global__ __launch_bounds__(512)
void gemm3b(const bf16_t* __restrict__ A, const bf16_t* __restrict__ Bt,
            const float* __restrict__ biasp, void* __restrict__ Cp,
            int M, int N, int K)
{
    // per buffer: A rows [0,128), B rows [128,384), 64 elems/row
    __shared__ bf16_t LS[3][384*64];

    const int tid  = threadIdx.x;
    const int wave = tid >> 6;          // 0..7
    const int lane = tid & 63;
    const int quad = lane >> 4;
    const int l16  = lane & 15;
    const int wm   = (wave >> 2) * 64;  // 2 M-groups x 64 rows
    const int wn   = (wave & 3) * 64;   // 4 N-groups x 64 cols

    // XCD-aware swizzle (both grids are multiples of 8)
    const int nwg = gridDim.x * gridDim.y;
    const int bid = blockIdx.y * gridDim.x + blockIdx.x;
    const int cpx = nwg >> 3;
    const int swz = (bid & 7) * cpx + (bid >> 3);
    const int nbx = N >> 8;
    const int m0  = (swz / nbx) * 128;
    const int n0  = (swz % nbx) * 256;

    const int NT = K >> 6;

    // staging: each wave stages 8 rows/chunk; src col pre-swizzled so linear
    // LDS dest ends up chunk-XOR-permuted: phys_chunk = log_chunk ^ ((row>>1)&7)
    const int srow = lane >> 3;                                  // 0..7
    const int sch  = (lane & 7) ^ ((wave*4 + (lane >> 4)) & 7);  // logical 16B chunk
    const bf16_t* aSrc = A  + (size_t)(m0 + wave*8 + srow)*K + sch*8;
    const bf16_t* bSrc = Bt + (size_t)(n0 + wave*8 + srow)*K + sch*8;

    const int fsw = (l16 >> 1) & 7;   // read-side swizzle (same involution)

    f32x4 acc[4][4] = {};

    auto stage = [&](int bi, int t) {   // 6 gload16/wave: A 2 chunks, B 4 chunks
        const bf16_t* ap = aSrc + t*64;
        const bf16_t* bp = bSrc + t*64;
        gload16(ap,               &LS[bi][(0         + wave*8)*64]);
        gload16(ap + (size_t)64*K, &LS[bi][(64        + wave*8)*64]);
        gload16(bp,               &LS[bi][(128 +   0 + wave*8)*64]);
        gload16(bp + (size_t)64*K, &LS[bi][(128 +  64 + wave*8)*64]);
        gload16(bp + (size_t)128*K,&LS[bi][(128 + 128 + wave*8)*64]);
        gload16(bp + (size_t)192*K,&LS[bi][(128 + 192 + wave*8)*64]);
    };

    // prologue: tiles 0,1 -> bufs 0,1; wait tile 0 (leave tile 1's 6 in flight)
    stage(0, 0);
    stage(1, 1);
    asm volatile("s_waitcnt vmcnt(6)" ::: "memory");
    BARRIER;

    int bi = 0;
    for (int t = 0; t < NT; ++t) {
        bf16x8 af[4][2], bfr[4][2];
        #pragma unroll
        for (int mi = 0; mi < 4; mi++)
            #pragma unroll
            for (int kk = 0; kk < 2; kk++)
                af[mi][kk] = *(const bf16x8*)
                    &LS[bi][(wm + mi*16 + l16)*64 + ((kk*4+quad)^fsw)*8];
        #pragma unroll
        for (int ni = 0; ni < 4; ni++)
            #pragma unroll
            for (int kk = 0; kk < 2; kk++)
                bfr[ni][kk] = *(const bf16x8*)
                    &LS[bi][(128 + wn + ni*16 + l16)*64 + ((kk*4+quad)^fsw)*8];

        if (t + 2 < NT) {
            int b2 = bi + 2; if (b2 >= 3) b2 -= 3;
            stage(b2, t + 2);
        }
        BARRIER;
        asm volatile("s_waitcnt lgkmcnt(0)" ::: "memory");
        __builtin_amdgcn_sched_barrier(0);
        __builtin_amdgcn_s_setprio(1);
        #pragma unroll
        for (int mi = 0; mi < 4; mi++)
            #pragma unroll
            for (int ni = 0; ni < 4; ni++)
                #pragma unroll
                for (int kk = 0; kk < 2; kk++)
                    acc[mi][ni] = mfma16(af[mi][kk], bfr[ni][kk], acc[mi][ni]);
        __builtin_amdgcn_s_setprio(0);
        // drain the batch consumed next phase; keep newest batch in flight
        if (t + 2 < NT)      asm volatile("s_waitcnt vmcnt(6)" ::: "memory");
        else if (t + 1 < NT) asm volatile("s_waitcnt vmcnt(0)" ::: "memory");
        BARRIER;
        bi = bi + 1; if (bi >= 3) bi = 0;
    }

    // ---- epilogue: bias + store
    float bv[4];
    #pragma unroll
    for (int ni = 0; ni < 4; ni++) bv[ni] = biasp[n0 + wn + ni*16 + l16];

    #pragma unroll
    for (int mi = 0; mi < 4; mi++)
        #pragma unroll
        for (int ni = 0; ni < 4; ni++)
            #pragma unroll
            for (int r = 0; r < 4; r++) {
                int row = m0 + wm + mi*16 + quad*4 + r;
                int col = n0 + wn + ni*16 + l16;
                float v = acc[mi][ni][r] + bv[ni];
                if (OUT_IS_F32) ((float*)Cp)[(size_t)row * N + col] = v;
                else            ((bf16_t*)Cp)[(size_t)row * N + col] = (bf16_t)v;
            }
}

// ---------------------------------------------------------------------------
// Flash attention v8 (known-good: 75.7us, MfmaUtil 37%). 128 VGPR / 2
// blocks/CU is the sweet spot (R2: forcing 4 blocks/CU spilled, 98.7us).
// S^T = K Q^T; p = exp2(s) packed bf16 in-register; O^T = V^T P^T via
// paired-K packing; epilogue through per-wave LDS tile -> coalesced stores.
// ---------------------------------------------------------------------------
__global__ __launch_bounds__(256, 2)
void attn8(const bf16_t* __restrict__ qkv, const bf16_t* __restrict__ vt,
           bf16_t* __restrict__ aout)
{
    __shared__ bf16_t Ks[64][72];      // [key][d]
    __shared__ bf16_t Vs[64][72];      // [d][key]
    __shared__ bf16_t Po[4][16][72];   // per-wave epilogue transpose tile

    const int tid  = threadIdx.x;
    const int wave = tid >> 6;
    const int lane = tid & 63;
    const int quad = lane >> 4;
    const int l16  = lane & 15;
    const int bh   = blockIdx.y;
    const int b    = bh >> 4;
    const int h    = bh & 15;
    const int qt   = blockIdx.x;       // 0..7 (256 q-rows each)
    const float kscale = 0.125f * 1.44269504088896340736f;

    // Q fragments (B-operand: n=q=l16, k=quad*8+j), pre-scaled by kscale
    bf16x8 qf[4][2];
    #pragma unroll
    for (int qi = 0; qi < 4; qi++) {
        const bf16_t* qrow = qkv + (size_t)(b*Sc + qt*256 + wave*64 + qi*16 + l16)*(3*Ec) + h*Dc;
        qf[qi][0] = *(const bf16x8*)(qrow + quad*8);
        qf[qi][1] = *(const bf16x8*)(qrow + 32 + quad*8);
        #pragma unroll
        for (int f = 0; f < 2; f++)
            #pragma unroll
            for (int e = 0; e < 8; e++)
                qf[qi][f][e] = (bf16_t)((float)qf[qi][f][e] * kscale);
    }

    f32x4 acc[4][4] = {};    // O^T accumulator [di][qi]: d=di*16+quad*4+r, q=qi*16+l16
    float lpart[4] = {};     // per-lane partial row sums (this quad's keys)

    const int krw   = tid >> 2;        // 0..63
    const int dbase = (tid & 3) * 16;  // 0/16/32/48

    const bf16_t* kbase = qkv + (size_t)(b*Sc + krw)*(3*Ec) + Ec + h*Dc + dbase;
    const bf16_t* vbase = vt + (size_t)bh*Dc*Sc + (size_t)krw*Sc + dbase;
    const size_t kstep = (size_t)64 * (3*Ec);
    uint4 ku0 = ((const uint4*)kbase)[0];
    uint4 ku1 = ((const uint4*)kbase)[1];
    uint4 vu0 = ((const uint4*)vbase)[0];
    uint4 vu1 = ((const uint4*)vbase)[1];

    for (int kt = 0; kt < Sc/64; kt++) {
        __syncthreads();
        *(uint4*)&Ks[krw][dbase]     = ku0;
        *(uint4*)&Ks[krw][dbase + 8] = ku1;
        *(uint4*)&Vs[krw][dbase]     = vu0;
        *(uint4*)&Vs[krw][dbase + 8] = vu1;
        __syncthreads();

        if (kt < Sc/64 - 1) {
            const bf16_t* kn = kbase + (size_t)(kt+1) * kstep;
            const bf16_t* vn = vbase + (kt+1) * 64;
            ku0 = ((const uint4*)kn)[0];
            ku1 = ((const uint4*)kn)[1];
            vu0 = ((const uint4*)vn)[0];
            vu1 = ((const uint4*)vn)[1];
        }

        // K fragments (A-operand: m=key=l16, k=quad*8+j)
        bf16x8 kf[4][2];
        #pragma unroll
        for (int ki = 0; ki < 4; ki++) {
            kf[ki][0] = *(const bf16x8*)&Ks[ki*16 + l16][quad*8];
            kf[ki][1] = *(const bf16x8*)&Ks[ki*16 + l16][32 + quad*8];
        }

        // S^T = K Q^T ; p = exp2(s) packed bf16, kept in registers
        bf16x4 pp[4][4];   // [ki][qi]: reg r = key ki*16+quad*4+r, col q=l16
        #pragma unroll
        for (int ki = 0; ki < 4; ki++) {
            #pragma unroll
            for (int qi = 0; qi < 4; qi++) {
                f32x4 z = {};
                z = mfma16(kf[ki][0], qf[qi][0], z);
                z = mfma16(kf[ki][1], qf[qi][1], z);
                float p0 = __ocml_native_exp2_f32(z[0]);
                float p1 = __ocml_native_exp2_f32(z[1]);
                float p2 = __ocml_native_exp2_f32(z[2]);
                float p3 = __ocml_native_exp2_f32(z[3]);
                lpart[qi] += (p0 + p1) + (p2 + p3);
                bf16x4 w;
                w[0] = (bf16_t)p0; w[1] = (bf16_t)p1;
                w[2] = (bf16_t)p2; w[3] = (bf16_t)p3;
                pp[ki][qi] = w;
            }
        }

        // O^T += V^T P^T : paired-K packing, keys c*32.. covered per c
        #pragma unroll
        for (int c = 0; c < 2; c++) {
            bf16x8 pcat[4];
            #pragma unroll
            for (int qi = 0; qi < 4; qi++)
                pcat[qi] = __builtin_shufflevector(pp[2*c][qi], pp[2*c+1][qi],
                                                   0,1,2,3,4,5,6,7);
            #pragma unroll
            for (int di = 0; di < 4; di++) {
                bf16x4 v0 = *(const bf16x4*)&Vs[di*16 + l16][c*32 + 4*quad];
                bf16x4 v1 = *(const bf16x4*)&Vs[di*16 + l16][c*32 + 16 + 4*quad];
                bf16x8 vf = __builtin_shufflevector(v0, v1, 0,1,2,3,4,5,6,7);
                #pragma unroll
                for (int qi = 0; qi < 4; qi++)
                    acc[di][qi] = mfma16(vf, pcat[qi], acc[di][qi]);
            }
        }
    }

    // ---- epilogue: reduce l across quads (keys), normalize, transpose via
    // per-wave LDS slice, coalesced stores ----
    float inv[4];
    #pragma unroll
    for (int qi = 0; qi < 4; qi++) {
        float l = lpart[qi];
        l += __shfl_xor(l, 16);
        l += __shfl_xor(l, 32);
        inv[qi] = 1.0f / l;
    }

    const int qrd  = lane >> 2;          // 0..15: token row within qi-slice
    const int dch  = (lane & 3) * 16;    // d chunk for read-back
    #pragma unroll
    for (int qi = 0; qi < 4; qi++) {
        // write O^T slice: Po[q=l16][d=di*16+quad*4 .. +3] (b64, 2-way free)
        #pragma unroll
        for (int di = 0; di < 4; di++) {
            alignas(8) bf16_t w[4];
            #pragma unroll
            for (int r = 0; r < 4; r++)
                w[r] = (bf16_t)(acc[di][qi][r] * inv[qi]);
            *(uint2*)&Po[wave][l16][di*16 + quad*4] = *(uint2*)w;
        }
        asm volatile("s_waitcnt lgkmcnt(0)" ::: "memory");
        // read back token-major, store coalesced (4 lanes = 128B per token)
        uint4 o0 = *(const uint4*)&Po[wave][qrd][dch];
        uint4 o1 = *(const uint4*)&Po[wave][qrd][dch + 8];
        bf16_t* dst = aout + (size_t)(b*Sc + qt*256 + wave*64 + qi*16 + qrd)*Ec + h*Dc + dch;
        ((uint4*)dst)[0] = o0;
        ((uint4*)dst)[1] = o1;
        // WAR safe across qi: DS pipe executes a wave's ops in order
    }
}

extern "C" void kernel_launch(void* const* d_in, const int* in_sizes, int n_in,
                              void* d_out, int out_size, void* d_ws, size_t ws_size,
                              hipStream_t stream) {
    const float* query = (const float*)d_in[0];
    const float* W_qkv = (const float*)d_in[3];
    const float* b_qkv = (const float*)d_in[4];
    const float* W_out = (const float*)d_in[5];
    const float* b_out = (const float*)d_in[6];
    float* out = (float*)d_out;

    const size_t MT = (size_t)Bc * Sc;             // 8192 tokens
    char* ws = (char*)d_ws;
    size_t off = 0;
    bf16_t* qbf    = (bf16_t*)(ws + off); off += MT*Ec*2;            // query bf16 / attn out
    bf16_t* qkv_ws = (bf16_t*)(ws + off); off += MT*3*Ec*2;
    bf16_t* vt_ws  = (bf16_t*)(ws + off); off += MT*Ec*2;
    bf16_t* wqkv_t = (bf16_t*)(ws + off); off += (size_t)3*Ec*Ec*2;
    bf16_t* wout_t = (bf16_t*)(ws + off); off += (size_t)Ec*Ec*2;

    cvt_bf16<<<(MT*Ec/4 + 255)/256, 256, 0, stream>>>(query, qbf, (int)(MT*Ec/4));
    transpose_w<<<dim3(3*Ec/64, Ec/64), 256, 0, stream>>>(W_qkv, wqkv_t, Ec, 3*Ec);
    transpose_w<<<dim3(Ec/64, Ec/64), 256, 0, stream>>>(W_out, wout_t, Ec, Ec);

    gemm3b<0><<<dim3(3*Ec/256, MT/128), 512, 0, stream>>>(
        qbf, wqkv_t, b_qkv, qkv_ws, (int)MT, 3*Ec, Ec);

    transpose_v<<<dim3(Sc/64, Bc*Hc), 256, 0, stream>>>(qkv_ws, vt_ws);

    attn8<<<dim3(Sc/256, Bc*Hc), 256, 0, stream>>>(qkv_ws, vt_ws, qbf);

    gemm3b<1><<<dim3(Ec/256, MT/128), 512, 0, stream>>>(
        qbf, wout_t, b_out, out, (int)MT, Ec, Ec);
}